// Round 1
// baseline (327.214 us; speedup 1.0000x reference)
//
#include <hip/hip_runtime.h>

// weight_noise: out[i] = noise[i] * GAMMA * sqrt(sum_k (2^k * bit_k(w))^2) / 2^WF
// where w = trunc(x[i] * 2^WF), GAMMA=0.05, WF=14.
// sum_k 4^k * bit_k(w) == zero-interleave (spread) of w's bits to even positions.
// Purely elementwise, memory-bound: 12 B/element of HBM traffic (402.6 MB/dispatch).
//
// R1: grid-stride with capped grid (2048 blocks) + x4 unroll (8 loads in flight
// per wave before first vmcnt wait) + nontemporal stores (output is never read;
// don't evict the streaming inputs from L2/L3). Previous version launched 32768
// one-shot blocks with only 2 loads/wave in flight -> latency-bound at 3.9 TB/s
// effective of ~6.3 achievable.

typedef float f4 __attribute__((ext_vector_type(4)));

__device__ __forceinline__ float sigma_of(float x) {
    // x in [0,1): trunc toward zero matches jnp astype(int32)
    unsigned w = (unsigned)(int)(x * 16384.0f);      // 14-bit value
    // spread bits: bit k -> bit 2k (handles up to 16 source bits)
    unsigned a = w;
    a = (a | (a << 8)) & 0x00FF00FFu;
    a = (a | (a << 4)) & 0x0F0F0F0Fu;
    a = (a | (a << 2)) & 0x33333333u;
    a = (a | (a << 1)) & 0x55555555u;
    // gamma * sqrt(acc) / 2^14  (power-of-two scale is exact)
    return (0.05f * sqrtf((float)a)) * (1.0f / 16384.0f);
}

__device__ __forceinline__ f4 body(f4 xv, f4 nv) {
    f4 ov;
    ov.x = nv.x * sigma_of(xv.x);
    ov.y = nv.y * sigma_of(xv.y);
    ov.z = nv.z * sigma_of(xv.z);
    ov.w = nv.w * sigma_of(xv.w);
    return ov;
}

__global__ __launch_bounds__(256, 8) void weight_noise_kernel(
    const f4* __restrict__ x4,
    const f4* __restrict__ n4,
    f4* __restrict__ o4,
    int count4)
{
    const int stride = gridDim.x * blockDim.x;           // 524288 lanes
    int i = blockIdx.x * blockDim.x + threadIdx.x;

    // Main unrolled-by-4 grid-stride loop: issue all 8 loads (x and n) before
    // any compute so the wave has 8x16B/lane = 8 KB in flight.
    // With count4 = 8388608 and stride = 524288 this runs exactly 4 times per
    // thread with no remainder.
    for (; i + 3 * stride < count4; i += 4 * stride) {
        f4 x0 = x4[i];
        f4 x1 = x4[i + stride];
        f4 x2 = x4[i + 2 * stride];
        f4 x3 = x4[i + 3 * stride];
        f4 n0 = n4[i];
        f4 n1 = n4[i + stride];
        f4 n2 = n4[i + 2 * stride];
        f4 n3 = n4[i + 3 * stride];
        __builtin_nontemporal_store(body(x0, n0), &o4[i]);
        __builtin_nontemporal_store(body(x1, n1), &o4[i + stride]);
        __builtin_nontemporal_store(body(x2, n2), &o4[i + 2 * stride]);
        __builtin_nontemporal_store(body(x3, n3), &o4[i + 3 * stride]);
    }
    // Remainder (not taken for the bench shape, kept for generality).
    for (; i < count4; i += stride) {
        __builtin_nontemporal_store(body(x4[i], n4[i]), &o4[i]);
    }
}

extern "C" void kernel_launch(void* const* d_in, const int* in_sizes, int n_in,
                              void* d_out, int out_size, void* d_ws, size_t ws_size,
                              hipStream_t stream) {
    const f4* x4 = (const f4*)d_in[0];       // x, float32
    const f4* nz = (const f4*)d_in[1];       // noise_n, float32
    f4* out = (f4*)d_out;                    // float32 output
    int n = in_sizes[0];                     // 4096*8192 = 33554432 (divisible by 4)
    int count4 = n / 4;
    int block = 256;
    long long grid_ll = (count4 + block - 1) / block;
    int grid = (grid_ll > 2048) ? 2048 : (int)grid_ll;   // cap + grid-stride
    weight_noise_kernel<<<grid, block, 0, stream>>>(x4, nz, out, count4);
}

// Round 2
// 304.548 us; speedup vs baseline: 1.0744x; 1.0744x over previous
//
#include <hip/hip_runtime.h>

// weight_noise: out[i] = noise[i] * GAMMA * sqrt(sum_k (2^k * bit_k(w))^2) / 2^WF
// where w = trunc(x[i] * 2^WF), GAMMA=0.05, WF=14.
// sum_k 4^k * bit_k(w) == zero-interleave (spread) of w's bits to even positions.
// Purely elementwise: 12 B/element ideal traffic (402.6 MB/dispatch; ~134 MB of
// reads served by L3 since one input stays resident across dispatches).
//
// R2: block-contiguous x4 unroll. R1 post-mortem: grid-stride w/ 8MB-separated
// chunks + VGPR=32 (too small to hold 8 in-flight f4 loads) meant the compiler
// serialized the unroll -> regression. Here each block owns a contiguous
// 1024-f4 (16KB/array) segment; thread t handles t, t+256, t+512, t+768.
// All 8 loads issue before any compute (needs ~50 VGPR; cap 64 via
// __launch_bounds__(256,8) keeps 8 waves/SIMD). Plain stores (nt was neutral
// on FETCH and confounded R1). Sequential block-ordered streaming preserved.

typedef float f4 __attribute__((ext_vector_type(4)));

__device__ __forceinline__ float sigma_of(float x) {
    // x in [0,1): trunc toward zero matches jnp astype(int32)
    unsigned w = (unsigned)(int)(x * 16384.0f);      // 14-bit value
    // spread bits: bit k -> bit 2k (handles up to 16 source bits)
    unsigned a = w;
    a = (a | (a << 8)) & 0x00FF00FFu;
    a = (a | (a << 4)) & 0x0F0F0F0Fu;
    a = (a | (a << 2)) & 0x33333333u;
    a = (a | (a << 1)) & 0x55555555u;
    // gamma * sqrt(acc) / 2^14  (power-of-two scale is exact)
    return (0.05f * sqrtf((float)a)) * (1.0f / 16384.0f);
}

__device__ __forceinline__ f4 body(f4 xv, f4 nv) {
    f4 ov;
    ov.x = nv.x * sigma_of(xv.x);
    ov.y = nv.y * sigma_of(xv.y);
    ov.z = nv.z * sigma_of(xv.z);
    ov.w = nv.w * sigma_of(xv.w);
    return ov;
}

__global__ __launch_bounds__(256, 8) void weight_noise_kernel(
    const f4* __restrict__ x4,
    const f4* __restrict__ n4,
    f4* __restrict__ o4,
    int count4)
{
    // Each block owns 1024 consecutive f4 elements (16 KB per array).
    int base = blockIdx.x * 1024 + threadIdx.x;

    if (base + 768 < count4) {
        // Fast path: issue all 8 loads (pairwise x/n so the first body's
        // operands return earliest), then compute, then store.
        f4 xv[4], nv[4];
        #pragma unroll
        for (int u = 0; u < 4; ++u) {
            xv[u] = x4[base + u * 256];
            nv[u] = n4[base + u * 256];
        }
        f4 ov[4];
        #pragma unroll
        for (int u = 0; u < 4; ++u) ov[u] = body(xv[u], nv[u]);
        #pragma unroll
        for (int u = 0; u < 4; ++u) o4[base + u * 256] = ov[u];
    } else {
        // Tail (not taken for the bench shape: 8388608 % 1024 == 0).
        for (int i = base; i < count4; i += 256) {
            o4[i] = body(x4[i], n4[i]);
        }
    }
}

extern "C" void kernel_launch(void* const* d_in, const int* in_sizes, int n_in,
                              void* d_out, int out_size, void* d_ws, size_t ws_size,
                              hipStream_t stream) {
    const f4* x4 = (const f4*)d_in[0];       // x, float32
    const f4* nz = (const f4*)d_in[1];       // noise_n, float32
    f4* out = (f4*)d_out;                    // float32 output
    int n = in_sizes[0];                     // 4096*8192 = 33554432
    int count4 = n / 4;                      // 8388608
    int block = 256;
    int per_block = 1024;                    // f4 elements per block
    int grid = (count4 + per_block - 1) / per_block;   // 8192 blocks
    weight_noise_kernel<<<grid, block, 0, stream>>>(x4, nz, out, count4);
}